// Round 4
// baseline (107.323 us; speedup 1.0000x reference)
//
#include <hip/hip_runtime.h>
#include <stdint.h>

#define INPUT_SCALE 0.0078125f   // 2^-7

__device__ __forceinline__ uint32_t sadu8(uint32_t a, uint32_t b, uint32_t c) {
#if __has_builtin(__builtin_amdgcn_sad_u8)
    return __builtin_amdgcn_sad_u8(a, b, c);
#else
    uint32_t d;
    asm("v_sad_u8 %0, %1, %2, %3" : "=v"(d) : "v"(a), "v"(b), "v"(c));
    return d;
#endif
}

__device__ __forceinline__ uint32_t qbyte(float x) {
    // round(clip(x*128, -127, 127)) + 128  (rintf = round-half-even, matches jnp.round)
    float v = fminf(fmaxf(x * 128.0f, -127.0f), 127.0f);
    return (uint32_t)((int)rintf(v) + 128);
}

// ---------------- Kernel A: weight scale + quantize + pack ----------------
// qwp layout: u = (f*9 + kpos)*8 + cg ; byte b of u32 = channel 4*cg+b, kpos = kh*3+kw
__global__ __launch_bounds__(1024) void quant_weight(const float* __restrict__ w,
                                                     uint32_t* __restrict__ qwp) {
    __shared__ float red[1024];
    __shared__ float s_inv;
    int tid = threadIdx.x;
    float m = 0.0f;
    for (int i = tid; i < 9216; i += 1024) m = fmaxf(m, fabsf(w[i]));
    red[tid] = m;
    __syncthreads();
    for (int s = 512; s > 0; s >>= 1) {
        if (tid < s) red[tid] = fmaxf(red[tid], red[tid + s]);
        __syncthreads();
    }
    if (tid == 0) {
        float s = fmaxf(red[0] / 127.0f, 1e-8f);
        int e; float fr = frexpf(s, &e);            // s = fr * 2^e, fr in [0.5,1)
        int k = (fr >= 0.70710678118654752f) ? e : e - 1;  // round(log2(s))
        s_inv = exp2f((float)(-k));                 // 1/s_w, exact power of 2
    }
    __syncthreads();
    float inv = s_inv;
    for (int u = tid; u < 2304; u += 1024) {
        int f = u / 72, rem = u % 72, kpos = rem / 8, cg = rem % 8;
        int kh = kpos / 3, kw = kpos % 3;
        uint32_t pk = 0;
        #pragma unroll
        for (int b = 0; b < 4; ++b) {
            int c = cg * 4 + b;
            float v = w[((f * 32 + c) * 3 + kh) * 3 + kw] * inv;
            v = fminf(fmaxf(v, -127.0f), 127.0f);
            pk |= ((uint32_t)((int)rintf(v) + 128) & 0xFFu) << (8 * b);
        }
        qwp[u] = pk;
    }
}

// ---------------- Kernel B: fused quantize + SAD conv ----------------
// Tile: 32 (w) x 8 (h). 512 threads = 256 px-threads x 2 filter-halves.
// Grid 1024 blocks -> 4 blocks/CU x 8 waves = 32 waves/CU.
// Loop nest: tap-outer (9, unrolled), filter-inner (16, unrolled) with acc[16]
// in VGPRs -> only 18 ds_read_b128 per thread (was 576).
// Weights: wave-uniform s_load_dwordx8 per (tap, f), scalar pipe.
#define LSTRIDE 12  // u32 per pixel slot (32B data + 16B pad)
__global__ __launch_bounds__(512, 8) void adder_conv_fused(const float* __restrict__ x,
                                                           const uint32_t* __restrict__ qwp,
                                                           float* __restrict__ out) {
    __shared__ __align__(16) uint32_t sx[10 * 34 * LSTRIDE];  // 16320 B
    int tid = threadIdx.x;
    int b = blockIdx.x;
    int n = b >> 6;
    int rem = b & 63;
    int h0 = (rem >> 2) * 8, w0 = (rem & 3) * 32;

    // quantize + pack the 10x34 halo (32 ch -> 8 u32/pixel) into LDS.
    // cg = q/340: a wave's lanes sweep consecutive pixels of one channel-group
    // -> coalesced contiguous float runs per (row, channel).
    for (int q = tid; q < 2720; q += 512) {          // 2720 = 340 px * 8 cg
        int cg = q / 340;
        int pixel = q - cg * 340;
        int r = pixel / 34, cc = pixel - r * 34;
        int gh = h0 - 1 + r, gw = w0 - 1 + cc;
        uint32_t pk = 0x80808080u;                   // quantized-zero padding
        if ((unsigned)gh < 128u && (unsigned)gw < 128u) {
            const float* base = x + (((size_t)n * 32 + cg * 4) * 128 + gh) * 128 + gw;
            pk = qbyte(base[0])
               | (qbyte(base[16384]) << 8)
               | (qbyte(base[32768]) << 16)
               | (qbyte(base[49152]) << 24);
        }
        sx[pixel * LSTRIDE + cg] = pk;
    }
    __syncthreads();

    int fh = tid >> 8;        // filter half: 0 -> f 0..15, 1 -> f 16..31
    int px = tid & 255;
    int r = px >> 5;          // row in tile 0..7
    int c = px & 31;          // col in tile

    const uint32_t* wfb = qwp + fh * 16 * 72;
    uint32_t acc[16];
    #pragma unroll
    for (int f = 0; f < 16; ++f) acc[f] = 0u;

    int lbase = (r * 34 + c) * LSTRIDE;
    #pragma unroll
    for (int t = 0; t < 9; ++t) {
        int kh = t / 3, kw = t - kh * 3;
        const uint4* p = (const uint4*)(sx + lbase + (kh * 34 + kw) * LSTRIDE);
        uint4 x0 = p[0];
        uint4 x1 = p[1];
        #pragma unroll
        for (int f = 0; f < 16; ++f) {
            const uint4* wp = (const uint4*)(wfb + (f * 9 + t) * 8);  // wave-uniform -> s_load
            uint4 wv0 = wp[0], wv1 = wp[1];
            uint32_t a = acc[f];
            a = sadu8(x0.x, wv0.x, a);
            a = sadu8(x0.y, wv0.y, a);
            a = sadu8(x0.z, wv0.z, a);
            a = sadu8(x0.w, wv0.w, a);
            a = sadu8(x1.x, wv1.x, a);
            a = sadu8(x1.y, wv1.y, a);
            a = sadu8(x1.z, wv1.z, a);
            a = sadu8(x1.w, wv1.w, a);
            acc[f] = a;
        }
    }

    size_t obase = (((size_t)n * 32 + fh * 16) * 128 + (h0 + r)) * 128 + (w0 + c);
    #pragma unroll
    for (int f = 0; f < 16; ++f) {
        out[obase + (size_t)f * 16384] = -(float)acc[f] * INPUT_SCALE;
    }
}

extern "C" void kernel_launch(void* const* d_in, const int* in_sizes, int n_in,
                              void* d_out, int out_size, void* d_ws, size_t ws_size,
                              hipStream_t stream) {
    const float* x = (const float*)d_in[0];       // (16,32,128,128)
    const float* w = (const float*)d_in[1];       // (32,32,3,3)
    float* out = (float*)d_out;                   // (16,32,128,128)

    uint32_t* qwp = (uint32_t*)d_ws;              // 9216 B

    quant_weight<<<1, 1024, 0, stream>>>(w, qwp);
    adder_conv_fused<<<1024, 512, 0, stream>>>(x, qwp, out);
}

// Round 5
// 95.380 us; speedup vs baseline: 1.1252x; 1.1252x over previous
//
#include <hip/hip_runtime.h>
#include <stdint.h>

#define INPUT_SCALE 0.0078125f   // 2^-7

__device__ __forceinline__ uint32_t sadu8(uint32_t a, uint32_t b, uint32_t c) {
#if __has_builtin(__builtin_amdgcn_sad_u8)
    return __builtin_amdgcn_sad_u8(a, b, c);
#else
    uint32_t d;
    asm("v_sad_u8 %0, %1, %2, %3" : "=v"(d) : "v"(a), "v"(b), "v"(c));
    return d;
#endif
}

__device__ __forceinline__ uint32_t qbyte(float x) {
    // round(clip(x*128, -127, 127)) + 128  (rintf = round-half-even, matches jnp.round)
    float v = fminf(fmaxf(x * 128.0f, -127.0f), 127.0f);
    return (uint32_t)((int)rintf(v) + 128);
}

// ---------------- Kernel A: weight scale + quantize + pack ----------------
// qwp layout: u = (f*9 + kpos)*8 + cg ; byte b of u32 = channel 4*cg+b, kpos = kh*3+kw
__global__ __launch_bounds__(1024) void quant_weight(const float* __restrict__ w,
                                                     uint32_t* __restrict__ qwp) {
    __shared__ float red[1024];
    __shared__ float s_inv;
    int tid = threadIdx.x;
    float m = 0.0f;
    for (int i = tid; i < 9216; i += 1024) m = fmaxf(m, fabsf(w[i]));
    red[tid] = m;
    __syncthreads();
    for (int s = 512; s > 0; s >>= 1) {
        if (tid < s) red[tid] = fmaxf(red[tid], red[tid + s]);
        __syncthreads();
    }
    if (tid == 0) {
        float s = fmaxf(red[0] / 127.0f, 1e-8f);
        int e; float fr = frexpf(s, &e);            // s = fr * 2^e, fr in [0.5,1)
        int k = (fr >= 0.70710678118654752f) ? e : e - 1;  // round(log2(s))
        s_inv = exp2f((float)(-k));                 // 1/s_w, exact power of 2
    }
    __syncthreads();
    float inv = s_inv;
    for (int u = tid; u < 2304; u += 1024) {
        int f = u / 72, rem = u % 72, kpos = rem / 8, cg = rem % 8;
        int kh = kpos / 3, kw = kpos % 3;
        uint32_t pk = 0;
        #pragma unroll
        for (int b = 0; b < 4; ++b) {
            int c = cg * 4 + b;
            float v = w[((f * 32 + c) * 3 + kh) * 3 + kw] * inv;
            v = fminf(fmaxf(v, -127.0f), 127.0f);
            pk |= ((uint32_t)((int)rintf(v) + 128) & 0xFFu) << (8 * b);
        }
        qwp[u] = pk;
    }
}

// ---------------- Kernel B: fused quantize + SAD conv ----------------
// Tile: 32 (w) x 8 (h). 512 threads = 256 px-threads x 2 filter-halves.
// Loop nest: tap-outer (9), filter-inner (16) with acc[16] in VGPRs ->
// 18 ds_read_b128 per thread. Weights: block-uniform -> s_load, scalar pipe.
// __launch_bounds__(512,4): 128-VGPR cap. (512,8) forced a 64-VGPR cap and
// the compiler spilled acc[16] to scratch (R4: WRITE_SIZE 2x, 109 us).
#define LSTRIDE 12  // u32 per pixel slot (32B data + 16B pad)
__global__ __launch_bounds__(512, 4) void adder_conv_fused(const float* __restrict__ x,
                                                           const uint32_t* __restrict__ qwp,
                                                           float* __restrict__ out) {
    __shared__ __align__(16) uint32_t sx[10 * 34 * LSTRIDE];  // 16320 B
    int tid = threadIdx.x;
    int b = blockIdx.x;
    int n = b >> 6;
    int rem = b & 63;
    int h0 = (rem >> 2) * 8, w0 = (rem & 3) * 32;

    // quantize + pack the 10x34 halo (32 ch -> 8 u32/pixel) into LDS.
    // cg = q/340: a wave's lanes sweep consecutive pixels of one channel-group
    // -> coalesced contiguous float runs per (row, channel).
    for (int q = tid; q < 2720; q += 512) {          // 2720 = 340 px * 8 cg
        int cg = q / 340;
        int pixel = q - cg * 340;
        int r = pixel / 34, cc = pixel - r * 34;
        int gh = h0 - 1 + r, gw = w0 - 1 + cc;
        uint32_t pk = 0x80808080u;                   // quantized-zero padding
        if ((unsigned)gh < 128u && (unsigned)gw < 128u) {
            const float* base = x + (((size_t)n * 32 + cg * 4) * 128 + gh) * 128 + gw;
            pk = qbyte(base[0])
               | (qbyte(base[16384]) << 8)
               | (qbyte(base[32768]) << 16)
               | (qbyte(base[49152]) << 24);
        }
        sx[pixel * LSTRIDE + cg] = pk;
    }
    __syncthreads();

    int fh = tid >> 8;        // filter half: 0 -> f 0..15, 1 -> f 16..31
    int px = tid & 255;
    int r = px >> 5;          // row in tile 0..7
    int c = px & 31;          // col in tile

    const uint32_t* wfb = qwp + fh * 16 * 72;
    uint32_t acc[16];
    #pragma unroll
    for (int f = 0; f < 16; ++f) acc[f] = 0u;

    int lbase = (r * 34 + c) * LSTRIDE;
    #pragma unroll
    for (int t = 0; t < 9; ++t) {
        int kh = t / 3, kw = t - kh * 3;
        const uint4* p = (const uint4*)(sx + lbase + (kh * 34 + kw) * LSTRIDE);
        uint4 x0 = p[0];
        uint4 x1 = p[1];
        #pragma unroll
        for (int f = 0; f < 16; ++f) {
            const uint4* wp = (const uint4*)(wfb + (f * 9 + t) * 8);  // block-uniform -> s_load
            uint4 wv0 = wp[0], wv1 = wp[1];
            uint32_t a = acc[f];
            a = sadu8(x0.x, wv0.x, a);
            a = sadu8(x0.y, wv0.y, a);
            a = sadu8(x0.z, wv0.z, a);
            a = sadu8(x0.w, wv0.w, a);
            a = sadu8(x1.x, wv1.x, a);
            a = sadu8(x1.y, wv1.y, a);
            a = sadu8(x1.z, wv1.z, a);
            a = sadu8(x1.w, wv1.w, a);
            acc[f] = a;
        }
    }

    size_t obase = (((size_t)n * 32 + fh * 16) * 128 + (h0 + r)) * 128 + (w0 + c);
    #pragma unroll
    for (int f = 0; f < 16; ++f) {
        out[obase + (size_t)f * 16384] = -(float)acc[f] * INPUT_SCALE;
    }
}

extern "C" void kernel_launch(void* const* d_in, const int* in_sizes, int n_in,
                              void* d_out, int out_size, void* d_ws, size_t ws_size,
                              hipStream_t stream) {
    const float* x = (const float*)d_in[0];       // (16,32,128,128)
    const float* w = (const float*)d_in[1];       // (32,32,3,3)
    float* out = (float*)d_out;                   // (16,32,128,128)

    uint32_t* qwp = (uint32_t*)d_ws;              // 9216 B

    quant_weight<<<1, 1024, 0, stream>>>(w, qwp);
    adder_conv_fused<<<1024, 512, 0, stream>>>(x, qwp, out);
}

// Round 6
// 58.111 us; speedup vs baseline: 1.8469x; 1.6413x over previous
//
#include <hip/hip_runtime.h>
#include <stdint.h>

#define INPUT_SCALE 0.0078125f   // 2^-7

__device__ __forceinline__ uint32_t sadu8(uint32_t a, uint32_t b, uint32_t c) {
#if __has_builtin(__builtin_amdgcn_sad_u8)
    return __builtin_amdgcn_sad_u8(a, b, c);
#else
    uint32_t d;
    asm("v_sad_u8 %0, %1, %2, %3" : "=v"(d) : "v"(a), "v"(b), "v"(c));
    return d;
#endif
}

__device__ __forceinline__ uint32_t qbyte(float x) {
    // round(clip(x*128, -127, 127)) + 128  (rintf = round-half-even, matches jnp.round)
    float v = fminf(fmaxf(x * 128.0f, -127.0f), 127.0f);
    return (uint32_t)((int)rintf(v) + 128);
}

// ---------------- Kernel A: weight scale + quantize + pack ----------------
// qwp layout: u = (f*9 + kpos)*8 + cg ; byte b of u32 = channel 4*cg+b, kpos = kh*3+kw
__global__ __launch_bounds__(1024) void quant_weight(const float* __restrict__ w,
                                                     uint32_t* __restrict__ qwp) {
    __shared__ float red[1024];
    __shared__ float s_inv;
    int tid = threadIdx.x;
    float m = 0.0f;
    for (int i = tid; i < 9216; i += 1024) m = fmaxf(m, fabsf(w[i]));
    red[tid] = m;
    __syncthreads();
    for (int s = 512; s > 0; s >>= 1) {
        if (tid < s) red[tid] = fmaxf(red[tid], red[tid + s]);
        __syncthreads();
    }
    if (tid == 0) {
        float s = fmaxf(red[0] / 127.0f, 1e-8f);
        int e; float fr = frexpf(s, &e);            // s = fr * 2^e, fr in [0.5,1)
        int k = (fr >= 0.70710678118654752f) ? e : e - 1;  // round(log2(s))
        s_inv = exp2f((float)(-k));                 // 1/s_w, exact power of 2
    }
    __syncthreads();
    float inv = s_inv;
    for (int u = tid; u < 2304; u += 1024) {
        int f = u / 72, rem = u % 72, kpos = rem / 8, cg = rem % 8;
        int kh = kpos / 3, kw = kpos % 3;
        uint32_t pk = 0;
        #pragma unroll
        for (int b = 0; b < 4; ++b) {
            int c = cg * 4 + b;
            float v = w[((f * 32 + c) * 3 + kh) * 3 + kw] * inv;
            v = fminf(fmaxf(v, -127.0f), 127.0f);
            pk |= ((uint32_t)((int)rintf(v) + 128) & 0xFFu) << (8 * b);
        }
        qwp[u] = pk;
    }
}

// ---------------- Kernel B: fused quantize + SAD conv ----------------
// Tile: 32 (w) x 8 (h). 512 threads = 256 px-threads x 2 filter-halves.
// Loop nest: tap-outer (9), filter-inner (16), acc[16] in VGPRs ->
// 18 ds_read_b128 per thread.
// fh (tid>>8) is wave-uniform but LLVM's divergence analysis can't see that;
// readfirstlane forces uniformity so weight derefs compile to s_load via K$
// (R5: without it they were 288 per-lane global_load_dwordx4 -> 96 us).
#define LSTRIDE 12  // u32 per pixel slot (32B data + 16B pad)
__global__ __launch_bounds__(512, 4) void adder_conv_fused(const float* __restrict__ x,
                                                           const uint32_t* __restrict__ qwp,
                                                           float* __restrict__ out) {
    __shared__ __align__(16) uint32_t sx[10 * 34 * LSTRIDE];  // 16320 B
    int tid = threadIdx.x;
    int b = blockIdx.x;
    int n = b >> 6;
    int rem = b & 63;
    int h0 = (rem >> 2) * 8, w0 = (rem & 3) * 32;

    // quantize + pack the 10x34 halo (32 ch -> 8 u32/pixel) into LDS.
    for (int q = tid; q < 2720; q += 512) {          // 2720 = 340 px * 8 cg
        int cg = q / 340;
        int pixel = q - cg * 340;
        int r = pixel / 34, cc = pixel - r * 34;
        int gh = h0 - 1 + r, gw = w0 - 1 + cc;
        uint32_t pk = 0x80808080u;                   // quantized-zero padding
        if ((unsigned)gh < 128u && (unsigned)gw < 128u) {
            const float* base = x + (((size_t)n * 32 + cg * 4) * 128 + gh) * 128 + gw;
            pk = qbyte(base[0])
               | (qbyte(base[16384]) << 8)
               | (qbyte(base[32768]) << 16)
               | (qbyte(base[49152]) << 24);
        }
        sx[pixel * LSTRIDE + cg] = pk;
    }
    __syncthreads();

    // filter half: wave-uniform; readfirstlane makes it provably uniform -> s_load weights
    int fh = __builtin_amdgcn_readfirstlane(tid >> 8);   // 0 -> f 0..15, 1 -> f 16..31
    int px = tid & 255;
    int r = px >> 5;          // row in tile 0..7
    int c = px & 31;          // col in tile

    const uint32_t* wfb = qwp + fh * 1152;   // uniform base
    uint32_t acc[16];
    #pragma unroll
    for (int f = 0; f < 16; ++f) acc[f] = 0u;

    int lbase = (r * 34 + c) * LSTRIDE;
    #pragma unroll
    for (int t = 0; t < 9; ++t) {
        int kh = t / 3, kw = t - kh * 3;
        const uint4* p = (const uint4*)(sx + lbase + (kh * 34 + kw) * LSTRIDE);
        uint4 x0 = p[0];
        uint4 x1 = p[1];
        #pragma unroll
        for (int f = 0; f < 16; ++f) {
            const uint4* wp = (const uint4*)(wfb + (f * 9 + t) * 8);  // uniform -> s_load
            uint4 wv0 = wp[0], wv1 = wp[1];
            uint32_t a = acc[f];
            a = sadu8(x0.x, wv0.x, a);
            a = sadu8(x0.y, wv0.y, a);
            a = sadu8(x0.z, wv0.z, a);
            a = sadu8(x0.w, wv0.w, a);
            a = sadu8(x1.x, wv1.x, a);
            a = sadu8(x1.y, wv1.y, a);
            a = sadu8(x1.z, wv1.z, a);
            a = sadu8(x1.w, wv1.w, a);
            acc[f] = a;
        }
    }

    size_t obase = (((size_t)n * 32 + fh * 16) * 128 + (h0 + r)) * 128 + (w0 + c);
    #pragma unroll
    for (int f = 0; f < 16; ++f) {
        out[obase + (size_t)f * 16384] = -(float)acc[f] * INPUT_SCALE;
    }
}

extern "C" void kernel_launch(void* const* d_in, const int* in_sizes, int n_in,
                              void* d_out, int out_size, void* d_ws, size_t ws_size,
                              hipStream_t stream) {
    const float* x = (const float*)d_in[0];       // (16,32,128,128)
    const float* w = (const float*)d_in[1];       // (32,32,3,3)
    float* out = (float*)d_out;                   // (16,32,128,128)

    uint32_t* qwp = (uint32_t*)d_ws;              // 9216 B

    quant_weight<<<1, 1024, 0, stream>>>(w, qwp);
    adder_conv_fused<<<1024, 512, 0, stream>>>(x, qwp, out);
}

// Round 7
// 56.326 us; speedup vs baseline: 1.9054x; 1.0317x over previous
//
#include <hip/hip_runtime.h>
#include <stdint.h>

#define INPUT_SCALE 0.0078125f   // 2^-7

__device__ __forceinline__ uint32_t sadu8(uint32_t a, uint32_t b, uint32_t c) {
#if __has_builtin(__builtin_amdgcn_sad_u8)
    return __builtin_amdgcn_sad_u8(a, b, c);
#else
    uint32_t d;
    asm("v_sad_u8 %0, %1, %2, %3" : "=v"(d) : "v"(a), "v"(b), "v"(c));
    return d;
#endif
}

__device__ __forceinline__ uint32_t qbyte(float x) {
    // round(clip(x*128, -127, 127)) + 128  (rintf = round-half-even, matches jnp.round)
    float v = fminf(fmaxf(x * 128.0f, -127.0f), 127.0f);
    return (uint32_t)((int)rintf(v) + 128);
}

// ---------------- Kernel A: weight scale + quantize + pack ----------------
// qwp layout: u = (f*9 + kpos)*8 + cg ; byte b of u32 = channel 4*cg+b, kpos = kh*3+kw
__global__ __launch_bounds__(1024) void quant_weight(const float* __restrict__ w,
                                                     uint32_t* __restrict__ qwp) {
    __shared__ float red[1024];
    __shared__ float s_inv;
    int tid = threadIdx.x;
    float m = 0.0f;
    for (int i = tid; i < 9216; i += 1024) m = fmaxf(m, fabsf(w[i]));
    red[tid] = m;
    __syncthreads();
    for (int s = 512; s > 0; s >>= 1) {
        if (tid < s) red[tid] = fmaxf(red[tid], red[tid + s]);
        __syncthreads();
    }
    if (tid == 0) {
        float s = fmaxf(red[0] / 127.0f, 1e-8f);
        int e; float fr = frexpf(s, &e);            // s = fr * 2^e, fr in [0.5,1)
        int k = (fr >= 0.70710678118654752f) ? e : e - 1;  // round(log2(s))
        s_inv = exp2f((float)(-k));                 // 1/s_w, exact power of 2
    }
    __syncthreads();
    float inv = s_inv;
    for (int u = tid; u < 2304; u += 1024) {
        int f = u / 72, rem = u % 72, kpos = rem / 8, cg = rem % 8;
        int kh = kpos / 3, kw = kpos % 3;
        uint32_t pk = 0;
        #pragma unroll
        for (int b = 0; b < 4; ++b) {
            int c = cg * 4 + b;
            float v = w[((f * 32 + c) * 3 + kh) * 3 + kw] * inv;
            v = fminf(fmaxf(v, -127.0f), 127.0f);
            pk |= ((uint32_t)((int)rintf(v) + 128) & 0xFFu) << (8 * b);
        }
        qwp[u] = pk;
    }
}

// ---------------- Kernel B: fused quantize + SAD conv ----------------
// Tile: 32 (w) x 8 (h). 256 threads = 4 waves; wave = one filter-group of 8.
// Lane owns 4 vertical pixels (col = lane&31, rows 4*(lane>>5)+0..3).
// Weights staged in LDS; all weight/pixel reads are ds_read_b128 -> in-order
// counted lgkmcnt waits (SMEM s_loads forced lgkmcnt(0) drains in R6: 28% VALU).
// Per tap: 8 pixel b128 + 16 broadcast weight b128 vs 256 sads -> DS ~55% of VALU.
// kh/kw runtime loops (unroll 1) keep pixel reads from being hoisted; f8/dr fully
// unrolled so acc[4][8] stays statically indexed (VGPRs, no scratch).
#define LSTRIDE 12  // u32 per pixel slot (32B data + 16B pad)
__global__ __launch_bounds__(256, 4) void adder_conv_fused(const float* __restrict__ x,
                                                           const uint32_t* __restrict__ qwp,
                                                           float* __restrict__ out) {
    __shared__ __align__(16) uint32_t sx[10 * 34 * LSTRIDE];  // 16320 B
    __shared__ __align__(16) uint4 sw4[576];                  // 9216 B: weights
    int tid = threadIdx.x;
    int b = blockIdx.x;
    int n = b >> 6;
    int rem = b & 63;
    int h0 = (rem >> 2) * 8, w0 = (rem & 3) * 32;

    // stage packed weights (uint4 granularity)
    for (int i = tid; i < 576; i += 256) sw4[i] = ((const uint4*)qwp)[i];

    // quantize + pack the 10x34 halo (32 ch -> 8 u32/pixel) into LDS.
    for (int q = tid; q < 2720; q += 256) {          // 2720 = 340 px * 8 cg
        int cg = q / 340;
        int pixel = q - cg * 340;
        int r = pixel / 34, cc = pixel - r * 34;
        int gh = h0 - 1 + r, gw = w0 - 1 + cc;
        uint32_t pk = 0x80808080u;                   // quantized-zero padding
        if ((unsigned)gh < 128u && (unsigned)gw < 128u) {
            const float* base = x + (((size_t)n * 32 + cg * 4) * 128 + gh) * 128 + gw;
            pk = qbyte(base[0])
               | (qbyte(base[16384]) << 8)
               | (qbyte(base[32768]) << 16)
               | (qbyte(base[49152]) << 24);
        }
        sx[pixel * LSTRIDE + cg] = pk;
    }
    __syncthreads();

    int fg   = __builtin_amdgcn_readfirstlane(tid >> 6);  // wave id = filter group
    int lane = tid & 63;
    int col  = lane & 31;
    int rq   = lane >> 5;        // row quad: rows rq*4 .. rq*4+3
    int fbase = fg * 8;

    uint32_t acc[4][8];
    #pragma unroll
    for (int dr = 0; dr < 4; ++dr)
        #pragma unroll
        for (int f8 = 0; f8 < 8; ++f8) acc[dr][f8] = 0u;

    int rowbase = rq * 4;
    #pragma unroll 1
    for (int kh = 0; kh < 3; ++kh) {
        #pragma unroll 1
        for (int kw = 0; kw < 3; ++kw) {
            // pixel neighborhood for this tap: 4 rows, fixed col
            uint4 px[4][2];
            #pragma unroll
            for (int dr = 0; dr < 4; ++dr) {
                const uint4* p = (const uint4*)(sx + ((rowbase + dr + kh) * 34 + (col + kw)) * LSTRIDE);
                px[dr][0] = p[0];
                px[dr][1] = p[1];
            }
            int t2 = (kh * 3 + kw) * 2;
            #pragma unroll
            for (int f8 = 0; f8 < 8; ++f8) {
                uint4 wv0 = sw4[(fbase + f8) * 18 + t2];
                uint4 wv1 = sw4[(fbase + f8) * 18 + t2 + 1];
                #pragma unroll
                for (int dr = 0; dr < 4; ++dr) {
                    uint32_t a = acc[dr][f8];
                    a = sadu8(px[dr][0].x, wv0.x, a);
                    a = sadu8(px[dr][0].y, wv0.y, a);
                    a = sadu8(px[dr][0].z, wv0.z, a);
                    a = sadu8(px[dr][0].w, wv0.w, a);
                    a = sadu8(px[dr][1].x, wv1.x, a);
                    a = sadu8(px[dr][1].y, wv1.y, a);
                    a = sadu8(px[dr][1].z, wv1.z, a);
                    a = sadu8(px[dr][1].w, wv1.w, a);
                    acc[dr][f8] = a;
                }
            }
        }
    }

    #pragma unroll
    for (int f8 = 0; f8 < 8; ++f8) {
        size_t obase = (((size_t)n * 32 + fbase + f8) * 128 + (h0 + rowbase)) * 128 + (w0 + col);
        #pragma unroll
        for (int dr = 0; dr < 4; ++dr) {
            out[obase + (size_t)dr * 128] = -(float)acc[dr][f8] * INPUT_SCALE;
        }
    }
}

extern "C" void kernel_launch(void* const* d_in, const int* in_sizes, int n_in,
                              void* d_out, int out_size, void* d_ws, size_t ws_size,
                              hipStream_t stream) {
    const float* x = (const float*)d_in[0];       // (16,32,128,128)
    const float* w = (const float*)d_in[1];       // (32,32,3,3)
    float* out = (float*)d_out;                   // (16,32,128,128)

    uint32_t* qwp = (uint32_t*)d_ws;              // 9216 B

    quant_weight<<<1, 1024, 0, stream>>>(w, qwp);
    adder_conv_fused<<<1024, 256, 0, stream>>>(x, qwp, out);
}

// Round 8
// 48.549 us; speedup vs baseline: 2.2106x; 1.1602x over previous
//
#include <hip/hip_runtime.h>
#include <stdint.h>

#define INPUT_SCALE 0.0078125f   // 2^-7

typedef __attribute__((ext_vector_type(4))) unsigned int u32x4;

__device__ __forceinline__ uint32_t sadu8(uint32_t a, uint32_t b, uint32_t c) {
#if __has_builtin(__builtin_amdgcn_sad_u8)
    return __builtin_amdgcn_sad_u8(a, b, c);
#else
    uint32_t d;
    asm("v_sad_u8 %0, %1, %2, %3" : "=v"(d) : "v"(a), "v"(b), "v"(c));
    return d;
#endif
}

__device__ __forceinline__ uint32_t qbyte(float x) {
    // round(clip(x*128, -127, 127)) + 128  (rintf = round-half-even, matches jnp.round)
    float v = fminf(fmaxf(x * 128.0f, -127.0f), 127.0f);
    return (uint32_t)((int)rintf(v) + 128);
}

// ---------------- Kernel A: weight scale + quantize + pack ----------------
// qwp layout: u = (f*9 + kpos)*8 + cg ; byte b of u32 = channel 4*cg+b, kpos = kh*3+kw
__global__ __launch_bounds__(1024) void quant_weight(const float* __restrict__ w,
                                                     uint32_t* __restrict__ qwp) {
    __shared__ float red[1024];
    __shared__ float s_inv;
    int tid = threadIdx.x;
    float m = 0.0f;
    for (int i = tid; i < 9216; i += 1024) m = fmaxf(m, fabsf(w[i]));
    red[tid] = m;
    __syncthreads();
    for (int s = 512; s > 0; s >>= 1) {
        if (tid < s) red[tid] = fmaxf(red[tid], red[tid + s]);
        __syncthreads();
    }
    if (tid == 0) {
        float s = fmaxf(red[0] / 127.0f, 1e-8f);
        int e; float fr = frexpf(s, &e);            // s = fr * 2^e, fr in [0.5,1)
        int k = (fr >= 0.70710678118654752f) ? e : e - 1;  // round(log2(s))
        s_inv = exp2f((float)(-k));                 // 1/s_w, exact power of 2
    }
    __syncthreads();
    float inv = s_inv;
    for (int u = tid; u < 2304; u += 1024) {
        int f = u / 72, rem = u % 72, kpos = rem / 8, cg = rem % 8;
        int kh = kpos / 3, kw = kpos % 3;
        uint32_t pk = 0;
        #pragma unroll
        for (int b = 0; b < 4; ++b) {
            int c = cg * 4 + b;
            float v = w[((f * 32 + c) * 3 + kh) * 3 + kw] * inv;
            v = fminf(fmaxf(v, -127.0f), 127.0f);
            pk |= ((uint32_t)((int)rintf(v) + 128) & 0xFFu) << (8 * b);
        }
        qwp[u] = pk;
    }
}

// ---------------- Kernel B: fused quantize + SAD conv ----------------
// Tile 32x16, 512 threads, 1 px/thread. Neighborhood (3x3 px x 32ch = 18 uint4)
// loaded ONCE via inline-asm ds_read_b128 -> pinned in 72 VGPRs (compiler cannot
// sink/remat volatile asm; R3's plain-C version re-read LDS per tap: DS-bound).
// f-loop: only v_sad_u8 + uniform qwp derefs (s_load -> SGPR operand, scalar pipe;
// no DS in flight so lgkmcnt waits are cheap). Per-thread DS: 216 -> 18 b128.
#define LSTRIDE 12  // u32 per pixel slot (32B data + 16B pad)
__global__ __launch_bounds__(512, 4) void adder_conv_fused(const float* __restrict__ x,
                                                           const uint32_t* __restrict__ qwp,
                                                           float* __restrict__ out) {
    __shared__ __align__(16) uint32_t sx[18 * 34 * LSTRIDE];  // 29376 B
    int tid = threadIdx.x;
    int b = blockIdx.x;
    int n = b >> 5;
    int rem = b & 31;
    int h0 = (rem >> 2) * 16, w0 = (rem & 3) * 32;

    // quantize + pack the 18x34 halo (32 ch -> 8 u32/pixel) into LDS.
    // cg = q/612: a wave's lanes sweep consecutive pixels of one channel-group
    // -> coalesced contiguous float runs per (row, channel).
    for (int q = tid; q < 4896; q += 512) {          // 4896 = 612 px * 8 cg
        int cg = q / 612;
        int pixel = q - cg * 612;
        int r = pixel / 34, cc = pixel - r * 34;
        int gh = h0 - 1 + r, gw = w0 - 1 + cc;
        uint32_t pk = 0x80808080u;                   // quantized-zero padding
        if ((unsigned)gh < 128u && (unsigned)gw < 128u) {
            const float* base = x + (((size_t)n * 32 + cg * 4) * 128 + gh) * 128 + gw;
            pk = qbyte(base[0])
               | (qbyte(base[16384]) << 8)
               | (qbyte(base[32768]) << 16)
               | (qbyte(base[49152]) << 24);
        }
        sx[pixel * LSTRIDE + cg] = pk;
    }
    __syncthreads();

    int c = tid & 31;    // col in tile
    int r = tid >> 5;    // row in tile 0..15

    // byte address of this thread's (r, c) halo corner in LDS
    uint32_t laddr = (uint32_t)(uintptr_t)(&sx[(r * 34 + c) * LSTRIDE]);

    u32x4 nb[3][3][2];   // 18 uint4 = 72 VGPRs, pinned by volatile asm
    #define LOADPX(dr, dc, i)                                                      \
        asm volatile("ds_read_b128 %0, %1 offset:%2"                               \
                     : "=v"(nb[dr][dc][i])                                         \
                     : "v"(laddr), "i"((((dr) * 34 + (dc)) * LSTRIDE + (i) * 4) * 4))
    LOADPX(0, 0, 0); LOADPX(0, 0, 1);
    LOADPX(0, 1, 0); LOADPX(0, 1, 1);
    LOADPX(0, 2, 0); LOADPX(0, 2, 1);
    LOADPX(1, 0, 0); LOADPX(1, 0, 1);
    LOADPX(1, 1, 0); LOADPX(1, 1, 1);
    LOADPX(1, 2, 0); LOADPX(1, 2, 1);
    LOADPX(2, 0, 0); LOADPX(2, 0, 1);
    LOADPX(2, 1, 0); LOADPX(2, 1, 1);
    LOADPX(2, 2, 0); LOADPX(2, 2, 1);
    #undef LOADPX
    asm volatile("s_waitcnt lgkmcnt(0)" ::: "memory");
    __builtin_amdgcn_sched_barrier(0);   // nothing crosses the wait (rule #18)

    size_t obase = ((size_t)(n * 32) * 128 + (h0 + r)) * 128 + (w0 + c);
    #pragma unroll 1
    for (int f = 0; f < 32; ++f) {
        const uint32_t* wf = qwp + f * 72;   // uniform -> s_load via K$
        uint32_t s0 = 0, s1 = 0, s2 = 0, s3 = 0;   // 4 independent sad chains
        #pragma unroll
        for (int t = 0; t < 9; ++t) {
            int kh = t / 3, kw = t - kh * 3;
            const uint4* wp = (const uint4*)(wf + t * 8);
            uint4 wv0 = wp[0], wv1 = wp[1];
            u32x4 x0 = nb[kh][kw][0], x1 = nb[kh][kw][1];
            s0 = sadu8(x0.x, wv0.x, s0);
            s1 = sadu8(x0.y, wv0.y, s1);
            s2 = sadu8(x0.z, wv0.z, s2);
            s3 = sadu8(x0.w, wv0.w, s3);
            s0 = sadu8(x1.x, wv1.x, s0);
            s1 = sadu8(x1.y, wv1.y, s1);
            s2 = sadu8(x1.z, wv1.z, s2);
            s3 = sadu8(x1.w, wv1.w, s3);
        }
        out[obase + (size_t)f * 16384] = -(float)((s0 + s1) + (s2 + s3)) * INPUT_SCALE;
    }
}

extern "C" void kernel_launch(void* const* d_in, const int* in_sizes, int n_in,
                              void* d_out, int out_size, void* d_ws, size_t ws_size,
                              hipStream_t stream) {
    const float* x = (const float*)d_in[0];       // (16,32,128,128)
    const float* w = (const float*)d_in[1];       // (32,32,3,3)
    float* out = (float*)d_out;                   // (16,32,128,128)

    uint32_t* qwp = (uint32_t*)d_ws;              // 9216 B

    quant_weight<<<1, 1024, 0, stream>>>(w, qwp);
    adder_conv_fused<<<512, 512, 0, stream>>>(x, qwp, out);
}